// Round 2
// baseline (220.946 us; speedup 1.0000x reference)
//
#include <hip/hip_runtime.h>

// ContinuousVariableQNN: out[b,i] = 0.25*(dsum[i] + mux^2 + mup^2) - 0.5
// mu = (2*inputs) @ (S[:,0::2])^T, S = prod_l (C @ D_l) via closed-form C.
// R2: prep fused into ONE kernel (64 blocks + device barrier); main GEMM single-bf16 1-pass.

#define BATCH 131072
#define NB 64  // prep grid size (all co-resident; 256 CUs)

typedef __attribute__((ext_vector_type(8))) short bf16x8;
typedef __attribute__((ext_vector_type(4))) float f32x4;

#define MFMA(a, b, c) __builtin_amdgcn_mfma_f32_16x16x32_bf16(a, b, c, 0, 0, 0)

__device__ __forceinline__ unsigned short f2bf(float f) {
  unsigned int u = __float_as_uint(f);
  u += 0x7FFFu + ((u >> 16) & 1u);
  return (unsigned short)(u >> 16);
}
__device__ __forceinline__ float bf2f(unsigned short h) {
  return __uint_as_float(((unsigned int)h) << 16);
}

// Device-scope barrier; counters zeroed by hipMemsetAsync each launch (one per sync point).
__device__ __forceinline__ void gbar(unsigned int* ctr) {
  __syncthreads();
  if (threadIdx.x == 0) {
    __threadfence();  // release prior writes to device scope
    __hip_atomic_fetch_add(ctr, 1u, __ATOMIC_ACQ_REL, __HIP_MEMORY_SCOPE_AGENT);
    while (__hip_atomic_load(ctr, __ATOMIC_ACQUIRE, __HIP_MEMORY_SCOPE_AGENT) < (unsigned)NB)
      __builtin_amdgcn_s_sleep(1);
  }
  __syncthreads();
  __threadfence();  // acquire: invalidate L1 so peers' data is visible
}

// One wave computes a 16x64 slice of a 256x256 product (split-bf16, 3-pass).
// L row-major [i][k]; R stored transposed [n][k]. Output hi/lo bf16 (row or col major) or f32.
__device__ void prod_subunit(const unsigned short* __restrict__ Lh,
                             const unsigned short* __restrict__ Ll,
                             const unsigned short* __restrict__ Rh,
                             const unsigned short* __restrict__ Rl,
                             int r0, int c0,
                             unsigned short* __restrict__ Oh,
                             unsigned short* __restrict__ Ol,
                             int row_major, float* __restrict__ Sout) {
  int lane = threadIdx.x & 63;
  int l15 = lane & 15, q = lane >> 4;
  f32x4 acc[4];
#pragma unroll
  for (int ct = 0; ct < 4; ++ct) acc[ct] = (f32x4){0.f, 0.f, 0.f, 0.f};
#pragma unroll
  for (int kc = 0; kc < 256; kc += 32) {
    int k = kc + q * 8;
    bf16x8 ah = *(const bf16x8*)(Lh + (r0 + l15) * 256 + k);
    bf16x8 al = *(const bf16x8*)(Ll + (r0 + l15) * 256 + k);
#pragma unroll
    for (int ct = 0; ct < 4; ++ct) {
      int n = c0 + ct * 16 + l15;
      bf16x8 bh = *(const bf16x8*)(Rh + n * 256 + k);
      bf16x8 bl = *(const bf16x8*)(Rl + n * 256 + k);
      acc[ct] = MFMA(ah, bh, acc[ct]);
      acc[ct] = MFMA(ah, bl, acc[ct]);
      acc[ct] = MFMA(al, bh, acc[ct]);
    }
  }
#pragma unroll
  for (int ct = 0; ct < 4; ++ct) {
    int j = c0 + ct * 16 + l15;
#pragma unroll
    for (int rg = 0; rg < 4; ++rg) {
      int i = r0 + q * 4 + rg;
      float v = acc[ct][rg];
      if (Sout) {
        Sout[i * 256 + j] = v;
      } else {
        unsigned short hi = f2bf(v);
        unsigned short lo = f2bf(v - bf2f(hi));
        int off = row_major ? (i * 256 + j) : (j * 256 + i);
        Oh[off] = hi;
        Ol[off] = lo;
      }
    }
  }
}

// ---------------- fused prep: build M -> tree products -> S -> pack W + dsum --
__global__ __launch_bounds__(256) void prep(const float* __restrict__ params,
                                            unsigned int* __restrict__ ctr,
                                            unsigned short* __restrict__ Mhi,
                                            unsigned short* __restrict__ Mlo,
                                            unsigned short* __restrict__ Phi,
                                            unsigned short* __restrict__ Plo,
                                            unsigned short* __restrict__ Qhi,
                                            unsigned short* __restrict__ Qlo,
                                            float* __restrict__ S,
                                            unsigned short* __restrict__ Wb,
                                            float* __restrict__ dsum) {
  int t = threadIdx.x;
  int lane = t & 63, w = t >> 6;
  int gw = blockIdx.x * 4 + w;  // 0..255

  // ---- Phase A: build M_l = C @ D_l (closed-form C). odd l row-major, even l transposed.
#pragma unroll 1
  for (int it = 0; it < 32; ++it) {
    int task = blockIdx.x * 32 + it;  // 0..2047
    int l = task >> 8, idx = task & 255;
    int i, j;
    if (l & 1) { i = idx; j = t; } else { j = idx; i = t; }
    int a = i >> 1, nn = j >> 1;
    float cx;
    if (a < 127) {
      if (nn == 0) cx = exp2f(-0.5f * (float)(a + 1));
      else if (nn <= a) cx = exp2f(-0.5f * (float)(a - nn + 2));
      else if (nn == a + 1) cx = -0.70710678118654752f;
      else cx = 0.0f;
    } else {
      cx = (nn == 0) ? exp2f(-63.5f) : exp2f(-0.5f * (float)(128 - nn));
    }
    const float* p = params + l * 384 + nn * 3;
    float th1 = p[0], r = p[1], th2 = p[2];
    float c1 = cosf(th1), s1 = sinf(th1);
    float c2 = cosf(th2), s2 = sinf(th2);
    float em = expf(-r), ep = expf(r);
    float bb;
    if (i & 1) bb = (j & 1) ? (-s2 * s1 * em + c2 * c1 * ep) : (s2 * c1 * em + c2 * s1 * ep);
    else       bb = (j & 1) ? (-c2 * s1 * em - s2 * c1 * ep) : (c2 * c1 * em - s2 * s1 * ep);
    float v = cx * bb;
    unsigned short hi = f2bf(v);
    unsigned short lo = f2bf(v - bf2f(hi));
    int off = l * 65536 + ((l & 1) ? (i * 256 + j) : (j * 256 + i));
    Mhi[off] = hi;
    Mlo[off] = lo;
  }
  gbar(ctr + 0);

  // ---- Level 1: P[p] = M[2p+1] @ M[2p], p=0..3; 256 sub-units.
  {
    int p = gw >> 6, ul = gw & 63;
    prod_subunit(Mhi + (2 * p + 1) * 65536, Mlo + (2 * p + 1) * 65536,
                 Mhi + (2 * p) * 65536, Mlo + (2 * p) * 65536,
                 (ul >> 2) * 16, (ul & 3) * 64,
                 Phi + p * 65536, Plo + p * 65536, p & 1, nullptr);
  }
  gbar(ctr + 1);

  // ---- Level 2: Q[p] = P[2p+1] @ P[2p], p=0..1; 128 sub-units.
  if (gw < 128) {
    int p = gw >> 6, ul = gw & 63;
    prod_subunit(Phi + (2 * p + 1) * 65536, Plo + (2 * p + 1) * 65536,
                 Phi + (2 * p) * 65536, Plo + (2 * p) * 65536,
                 (ul >> 2) * 16, (ul & 3) * 64,
                 Qhi + p * 65536, Qlo + p * 65536, p & 1, nullptr);
  }
  gbar(ctr + 2);

  // ---- Level 3: S = Q1 @ Q0 (f32 out); 64 sub-units.
  if (gw < 64) {
    int ul = gw & 63;
    prod_subunit(Qhi + 65536, Qlo + 65536, Qhi, Qlo,
                 (ul >> 2) * 16, (ul & 3) * 64, nullptr, nullptr, 0, S);
  }
  gbar(ctr + 3);

  // ---- Phase E: pack W (single bf16, B-frag order) + dsum.
  if (gw < 64) {
    int ct = gw >> 2, ks = gw & 3;
    int n = ct * 16 + (lane & 15);
    int k0 = ks * 32 + (lane >> 4) * 8;
    int srow = (n < 128) ? (2 * n) : (2 * (n - 128) + 1);
    unsigned int wd[4];
#pragma unroll
    for (int p2 = 0; p2 < 4; ++p2) {
      unsigned short h0 = f2bf(2.0f * S[srow * 256 + 2 * (k0 + 2 * p2)]);
      unsigned short h1 = f2bf(2.0f * S[srow * 256 + 2 * (k0 + 2 * p2 + 1)]);
      wd[p2] = (unsigned int)h0 | ((unsigned int)h1 << 16);
    }
    *(uint4*)(Wb + ((ct * 4 + ks) * 64 + lane) * 8) = make_uint4(wd[0], wd[1], wd[2], wd[3]);
  }
  __shared__ float sred[4];
  for (int h = 0; h < 2; ++h) {
    int i = blockIdx.x * 2 + h;  // 0..127
    const float* r0 = S + (2 * i) * 256;
    const float* r1 = r0 + 256;
    float s = r0[t] * r0[t] + r1[t] * r1[t];
#pragma unroll
    for (int off = 32; off; off >>= 1) s += __shfl_down(s, off);
    __syncthreads();
    if (lane == 0) sred[w] = s;
    __syncthreads();
    if (t == 0) dsum[i] = sred[0] + sred[1] + sred[2] + sred[3];
  }
}

// ---------------- main batched GEMM + fused epilogue (single bf16, 1 pass) ----
__global__ __launch_bounds__(256) void qnn_gemm(
    const float* __restrict__ A, const unsigned short* __restrict__ Wb,
    const float* __restrict__ dsum, float* __restrict__ out) {
  __shared__ unsigned short sA[64 * 136];  // 64 rows x 128 k (+8 pad)
  int t = threadIdx.x;
  int lane = t & 63, w = t >> 6;
  int wr = w >> 1, wc = w & 1;
  int l15 = lane & 15, q = lane >> 4;
  long brow0 = (long)blockIdx.x * 64;

  // Stage A tile fp32 -> bf16, coalesced float4 loads
#pragma unroll
  for (int it = 0; it < 8; ++it) {
    int e = it * 1024 + t * 4;
    int row = e >> 7, k = e & 127;
    float4 v = *(const float4*)(A + brow0 * 128 + e);
    *(uint2*)(sA + row * 136 + k) = make_uint2(
        (unsigned int)f2bf(v.x) | ((unsigned int)f2bf(v.y) << 16),
        (unsigned int)f2bf(v.z) | ((unsigned int)f2bf(v.w) << 16));
  }
  __syncthreads();

  f32x4 acc[2][4][2];
#pragma unroll
  for (int rt = 0; rt < 2; ++rt)
#pragma unroll
    for (int qq = 0; qq < 4; ++qq)
#pragma unroll
      for (int xp = 0; xp < 2; ++xp) acc[rt][qq][xp] = (f32x4){0.f, 0.f, 0.f, 0.f};

#pragma unroll
  for (int ks = 0; ks < 4; ++ks) {
    int kb = ks * 32 + q * 8;
    bf16x8 a0 = *(const bf16x8*)(sA + (wr * 32 + l15) * 136 + kb);
    bf16x8 a1 = *(const bf16x8*)(sA + (wr * 32 + 16 + l15) * 136 + kb);
#pragma unroll
    for (int qq = 0; qq < 4; ++qq)
#pragma unroll
      for (int xp = 0; xp < 2; ++xp) {
        int ct = wc * 4 + qq + 8 * xp;
        bf16x8 b = *(const bf16x8*)(Wb + ((ct * 4 + ks) * 64 + lane) * 8);
        acc[0][qq][xp] = MFMA(a0, b, acc[0][qq][xp]);
        acc[1][qq][xp] = MFMA(a1, b, acc[1][qq][xp]);
      }
  }

  // Fused epilogue: out = 0.25*(dsum + mux^2 + mup^2) - 0.5
#pragma unroll
  for (int qq = 0; qq < 4; ++qq) {
    int i = (wc * 4 + qq) * 16 + l15;
    float ds = dsum[i];
#pragma unroll
    for (int rt = 0; rt < 2; ++rt) {
      long row0 = brow0 + wr * 32 + rt * 16 + q * 4;
      f32x4 ax = acc[rt][qq][0];
      f32x4 ap = acc[rt][qq][1];
#pragma unroll
      for (int rg = 0; rg < 4; ++rg) {
        float val = 0.25f * (ds + ax[rg] * ax[rg] + ap[rg] * ap[rg]) - 0.5f;
        out[(row0 + rg) * 128 + i] = val;
      }
    }
  }
}

// ---------------- launcher ----------------------------------------------------
extern "C" void kernel_launch(void* const* d_in, const int* in_sizes, int n_in,
                              void* d_out, int out_size, void* d_ws, size_t ws_size,
                              hipStream_t stream) {
  const float* inputs = (const float*)d_in[0];   // [131072][128] f32
  const float* params = (const float*)d_in[1];   // [8][384] f32
  float* out = (float*)d_out;                    // [131072][128] f32

  unsigned int* ctr = (unsigned int*)d_ws;                 // 4 barrier counters (256 B reserved)
  unsigned short* base = (unsigned short*)((char*)d_ws + 256);
  unsigned short* Mhi = base;                              // 8*65536 shorts
  unsigned short* Mlo = Mhi + 8 * 65536;
  unsigned short* Phi = Mlo + 8 * 65536;                   // 4*65536
  unsigned short* Plo = Phi + 4 * 65536;
  unsigned short* Qhi = Plo + 4 * 65536;                   // 2*65536
  unsigned short* Qlo = Qhi + 2 * 65536;
  float* S = (float*)(Qlo + 2 * 65536);                    // 65536 f32
  unsigned short* Wb = (unsigned short*)(S + 65536);       // 65536 shorts
  float* dsum = (float*)(Wb + 65536);                      // 128 f32
  // total ws use ~3.9 MiB

  hipMemsetAsync(d_ws, 0, 256, stream);  // zero barrier counters (ws re-poisoned each launch)
  prep<<<NB, 256, 0, stream>>>(params, ctr, Mhi, Mlo, Phi, Plo, Qhi, Qlo, S, Wb, dsum);
  qnn_gemm<<<2048, 256, 0, stream>>>(inputs, Wb, dsum, out);
}

// Round 4
// 184.173 us; speedup vs baseline: 1.1997x; 1.1997x over previous
//
#include <hip/hip_runtime.h>

// ContinuousVariableQNN: out[b,i] = 0.25*(dsum[i] + mux^2 + mup^2) - 0.5
// mu = (2*inputs) @ (S[:,0::2])^T, S = prod_l (C @ D_l) via closed-form C.
// R3b: same as R3 (4 stream-ordered kernels, no device barriers) with the
// nontemporal load fixed to use a clang ext_vector float4.

#define BATCH 131072
#define PSTR 40  // 32 k + 8 pad (shorts); row stride 80 B

typedef __attribute__((ext_vector_type(8))) short bf16x8;
typedef __attribute__((ext_vector_type(4))) float f32x4;

#define MFMA(a, b, c) __builtin_amdgcn_mfma_f32_16x16x32_bf16(a, b, c, 0, 0, 0)

__device__ __forceinline__ unsigned short f2bf(float f) {
  unsigned int u = __float_as_uint(f);
  u += 0x7FFFu + ((u >> 16) & 1u);
  return (unsigned short)(u >> 16);
}
__device__ __forceinline__ float bf2f(unsigned short h) {
  return __uint_as_float(((unsigned int)h) << 16);
}
__device__ __forceinline__ void pack8(const float* v, uint4& hv, uint4& lv) {
  unsigned int hw[4], lw[4];
#pragma unroll
  for (int p = 0; p < 4; ++p) {
    unsigned short h0 = f2bf(v[2 * p]), h1 = f2bf(v[2 * p + 1]);
    unsigned short l0 = f2bf(v[2 * p] - bf2f(h0)), l1 = f2bf(v[2 * p + 1] - bf2f(h1));
    hw[p] = (unsigned int)h0 | ((unsigned int)h1 << 16);
    lw[p] = (unsigned int)l0 | ((unsigned int)l1 << 16);
  }
  hv = make_uint4(hw[0], hw[1], hw[2], hw[3]);
  lv = make_uint4(lw[0], lw[1], lw[2], lw[3]);
}

// Closed-form C entry magnitude: powc[m] = 2^(-m/2) = c^m.
__device__ __forceinline__ float cxf(const float* powc, int a, int nn) {
  if (a < 127) {
    if (nn == 0) return powc[a + 1];
    if (nn <= a) return powc[a - nn + 2];
    if (nn == a + 1) return -0.70710678118654752f;
    return 0.0f;
  }
  return (nn == 0) ? powc[127] : powc[128 - nn];
}

// ============ K1: P[p] = M[2p+1] @ M[2p], M chunks built in-LDS =============
// 16 blocks: (pair, tile). Output P hi/lo: p odd row-major, p even col-major.
__global__ __launch_bounds__(256) void l1_prod(const float* __restrict__ params,
                                               unsigned short* __restrict__ Phi,
                                               unsigned short* __restrict__ Plo) {
  __shared__ __align__(16) char lds_raw[4 * 128 * PSTR * 2];  // 40960 B staging / sEp
  __shared__ float blkA[128][4];  // 2x2 local blocks of layer 2p+1 (A side)
  __shared__ float blkB[128][4];  // layer 2p (B side)
  __shared__ float powc[132];
  unsigned short* sLhi = (unsigned short*)lds_raw;
  unsigned short* sLlo = sLhi + 128 * PSTR;
  unsigned short* sRhi = sLlo + 128 * PSTR;
  unsigned short* sRlo = sRhi + 128 * PSTR;
  float* sEp = (float*)lds_raw;  // epilogue [64][129]

  int bx = blockIdx.x;
  int pair = bx >> 2, tile = bx & 3;
  int tr = tile >> 1, tc = tile & 1;
  int t = threadIdx.x;
  int lane = t & 63, w = t >> 6;
  int wr = (w >> 1) * 64, wc = (w & 1) * 64;
  int l15 = lane & 15, q = lane >> 4;

  // Phase 0: per-mode 2x2 blocks (one trig round) + power table.
  {
    int l = (t < 128) ? (2 * pair + 1) : (2 * pair);
    int nn = t & 127;
    const float* p = params + l * 384 + nn * 3;
    float th1 = p[0], r = p[1], th2 = p[2];
    float c1 = cosf(th1), s1 = sinf(th1);
    float c2 = cosf(th2), s2 = sinf(th2);
    float em = expf(-r), ep = expf(r);
    float* dst = (t < 128) ? blkA[nn] : blkB[nn];
    dst[0] = c2 * c1 * em - s2 * s1 * ep;   // [i&1=0][j&1=0]
    dst[1] = -c2 * s1 * em - s2 * c1 * ep;  // [0][1]
    dst[2] = s2 * c1 * em + c2 * s1 * ep;   // [1][0]
    dst[3] = -s2 * s1 * em + c2 * c1 * ep;  // [1][1]
    if (t < 132) powc[t] = exp2f(-0.5f * (float)t);
  }

  f32x4 acc[4][4];
#pragma unroll
  for (int a = 0; a < 4; ++a)
#pragma unroll
    for (int b = 0; b < 4; ++b) acc[a][b] = (f32x4){0.f, 0.f, 0.f, 0.f};

  for (int kc = 0; kc < 256; kc += 32) {
    __syncthreads();
#pragma unroll
    for (int it = 0; it < 2; ++it) {
      int e = it * 2048 + t * 8;
      int row = e >> 5, k0 = e & 31;
      // A-chunk: M_{2p+1}(i = tr*128+row, j = kc+k0+jj)   (row-major role)
      {
        int i = tr * 128 + row;
        int a = i >> 1;
        float vv[8];
#pragma unroll
        for (int jj = 0; jj < 8; ++jj) {
          int j = kc + k0 + jj;
          int nn = j >> 1;
          vv[jj] = cxf(powc, a, nn) * blkA[nn][(i & 1) * 2 + (j & 1)];
        }
        uint4 hv, lv;
        pack8(vv, hv, lv);
        *(uint4*)(sLhi + row * PSTR + k0) = hv;
        *(uint4*)(sLlo + row * PSTR + k0) = lv;
      }
      // B-chunk: sR[row][k] = M_{2p}(i = kc+k0+jj, j = tc*128+row)  ([n][k] role)
      {
        int j = tc * 128 + row;
        int nn = j >> 1;
        float b0 = blkB[nn][0 + (j & 1)];
        float b1 = blkB[nn][2 + (j & 1)];
        float vv[8];
#pragma unroll
        for (int jj = 0; jj < 8; ++jj) {
          int i = kc + k0 + jj;
          vv[jj] = cxf(powc, i >> 1, nn) * ((i & 1) ? b1 : b0);
        }
        uint4 hv, lv;
        pack8(vv, hv, lv);
        *(uint4*)(sRhi + row * PSTR + k0) = hv;
        *(uint4*)(sRlo + row * PSTR + k0) = lv;
      }
    }
    __syncthreads();
    int kb = q * 8;
    bf16x8 afh[4], afl[4], bfh[4], bfl[4];
#pragma unroll
    for (int rt = 0; rt < 4; ++rt) {
      int r = wr + rt * 16 + l15;
      afh[rt] = *(const bf16x8*)(sLhi + r * PSTR + kb);
      afl[rt] = *(const bf16x8*)(sLlo + r * PSTR + kb);
      int n = wc + rt * 16 + l15;
      bfh[rt] = *(const bf16x8*)(sRhi + n * PSTR + kb);
      bfl[rt] = *(const bf16x8*)(sRlo + n * PSTR + kb);
    }
#pragma unroll
    for (int rt = 0; rt < 4; ++rt)
#pragma unroll
      for (int ct = 0; ct < 4; ++ct) {
        acc[rt][ct] = MFMA(afh[rt], bfh[ct], acc[rt][ct]);
        acc[rt][ct] = MFMA(afh[rt], bfl[ct], acc[rt][ct]);
        acc[rt][ct] = MFMA(afl[rt], bfh[ct], acc[rt][ct]);
      }
  }

  // Epilogue: hi/lo split store, row-major if pair odd else col-major.
  for (int ph = 0; ph < 2; ++ph) {
    __syncthreads();
    if (wr == ph * 64) {
#pragma unroll
      for (int rt = 0; rt < 4; ++rt)
#pragma unroll
        for (int ct = 0; ct < 4; ++ct) {
          int rl = rt * 16 + q * 4;
          int col = wc + ct * 16 + l15;
#pragma unroll
          for (int rg = 0; rg < 4; ++rg) sEp[(rl + rg) * 129 + col] = acc[rt][ct][rg];
        }
    }
    __syncthreads();
    if (pair & 1) {
      int rl = t >> 2, cseg = (t & 3) * 32;
      for (int cc = 0; cc < 32; cc += 8) {
        float v[8];
#pragma unroll
        for (int jj = 0; jj < 8; ++jj) v[jj] = sEp[rl * 129 + cseg + cc + jj];
        uint4 hv, lv;
        pack8(v, hv, lv);
        int off = pair * 65536 + (tr * 128 + ph * 64 + rl) * 256 + tc * 128 + cseg + cc;
        *(uint4*)(Phi + off) = hv;
        *(uint4*)(Plo + off) = lv;
      }
    } else {
      int col = t >> 1, rseg = (t & 1) * 32;
      for (int cc = 0; cc < 32; cc += 8) {
        float v[8];
#pragma unroll
        for (int jj = 0; jj < 8; ++jj) v[jj] = sEp[(rseg + cc + jj) * 129 + col];
        uint4 hv, lv;
        pack8(v, hv, lv);
        int off = pair * 65536 + (tc * 128 + col) * 256 + tr * 128 + ph * 64 + rseg + cc;
        *(uint4*)(Phi + off) = hv;
        *(uint4*)(Plo + off) = lv;
      }
    }
  }
}

// ============ K2: Q[p] = P[2p+1] @ P[2p] (generic, LDS-staged) ==============
__global__ __launch_bounds__(256) void matprod(
    const unsigned short* __restrict__ Lhi_base, const unsigned short* __restrict__ Llo_base,
    unsigned short* __restrict__ Ohi, unsigned short* __restrict__ Olo) {
  __shared__ __align__(16) char lds_raw[4 * 128 * PSTR * 2];
  unsigned short* sLhi = (unsigned short*)lds_raw;
  unsigned short* sLlo = sLhi + 128 * PSTR;
  unsigned short* sRhi = sLlo + 128 * PSTR;
  unsigned short* sRlo = sRhi + 128 * PSTR;
  float* sEp = (float*)lds_raw;

  int bx = blockIdx.x;
  int pair = bx >> 2, tile = bx & 3;
  int tr = tile >> 1, tc = tile & 1;
  const unsigned short* Lhi = Lhi_base + (2 * pair + 1) * 65536;  // row-major
  const unsigned short* Llo = Llo_base + (2 * pair + 1) * 65536;
  const unsigned short* Rhi = Lhi_base + (2 * pair) * 65536;      // col-major [n][k]
  const unsigned short* Rlo = Llo_base + (2 * pair) * 65536;

  int t = threadIdx.x;
  int lane = t & 63, w = t >> 6;
  int wr = (w >> 1) * 64, wc = (w & 1) * 64;
  int l15 = lane & 15, q = lane >> 4;

  f32x4 acc[4][4];
#pragma unroll
  for (int a = 0; a < 4; ++a)
#pragma unroll
    for (int b = 0; b < 4; ++b) acc[a][b] = (f32x4){0.f, 0.f, 0.f, 0.f};

  for (int kc = 0; kc < 256; kc += 32) {
    __syncthreads();
#pragma unroll
    for (int it = 0; it < 2; ++it) {
      int e = it * 2048 + t * 8;
      int row = e >> 5, k = e & 31;
      *(uint4*)(sLhi + row * PSTR + k) = *(const uint4*)(Lhi + (tr * 128 + row) * 256 + kc + k);
      *(uint4*)(sLlo + row * PSTR + k) = *(const uint4*)(Llo + (tr * 128 + row) * 256 + kc + k);
      *(uint4*)(sRhi + row * PSTR + k) = *(const uint4*)(Rhi + (tc * 128 + row) * 256 + kc + k);
      *(uint4*)(sRlo + row * PSTR + k) = *(const uint4*)(Rlo + (tc * 128 + row) * 256 + kc + k);
    }
    __syncthreads();
    int kb = q * 8;
    bf16x8 afh[4], afl[4], bfh[4], bfl[4];
#pragma unroll
    for (int rt = 0; rt < 4; ++rt) {
      int r = wr + rt * 16 + l15;
      afh[rt] = *(const bf16x8*)(sLhi + r * PSTR + kb);
      afl[rt] = *(const bf16x8*)(sLlo + r * PSTR + kb);
      int n = wc + rt * 16 + l15;
      bfh[rt] = *(const bf16x8*)(sRhi + n * PSTR + kb);
      bfl[rt] = *(const bf16x8*)(sRlo + n * PSTR + kb);
    }
#pragma unroll
    for (int rt = 0; rt < 4; ++rt)
#pragma unroll
      for (int ct = 0; ct < 4; ++ct) {
        acc[rt][ct] = MFMA(afh[rt], bfh[ct], acc[rt][ct]);
        acc[rt][ct] = MFMA(afh[rt], bfl[ct], acc[rt][ct]);
        acc[rt][ct] = MFMA(afl[rt], bfh[ct], acc[rt][ct]);
      }
  }

  for (int ph = 0; ph < 2; ++ph) {
    __syncthreads();
    if (wr == ph * 64) {
#pragma unroll
      for (int rt = 0; rt < 4; ++rt)
#pragma unroll
        for (int ct = 0; ct < 4; ++ct) {
          int rl = rt * 16 + q * 4;
          int col = wc + ct * 16 + l15;
#pragma unroll
          for (int rg = 0; rg < 4; ++rg) sEp[(rl + rg) * 129 + col] = acc[rt][ct][rg];
        }
    }
    __syncthreads();
    if (pair & 1) {
      int rl = t >> 2, cseg = (t & 3) * 32;
      for (int cc = 0; cc < 32; cc += 8) {
        float v[8];
#pragma unroll
        for (int jj = 0; jj < 8; ++jj) v[jj] = sEp[rl * 129 + cseg + cc + jj];
        uint4 hv, lv;
        pack8(v, hv, lv);
        int off = pair * 65536 + (tr * 128 + ph * 64 + rl) * 256 + tc * 128 + cseg + cc;
        *(uint4*)(Ohi + off) = hv;
        *(uint4*)(Olo + off) = lv;
      }
    } else {
      int col = t >> 1, rseg = (t & 1) * 32;
      for (int cc = 0; cc < 32; cc += 8) {
        float v[8];
#pragma unroll
        for (int jj = 0; jj < 8; ++jj) v[jj] = sEp[(rseg + cc + jj) * 129 + col];
        uint4 hv, lv;
        pack8(v, hv, lv);
        int off = pair * 65536 + (tc * 128 + col) * 256 + tr * 128 + ph * 64 + rseg + cc;
        *(uint4*)(Ohi + off) = hv;
        *(uint4*)(Olo + off) = lv;
      }
    }
  }
}

// ============ K3: S-tile = Q1 @ Q0, fused pack_W + dsum partials ============
// 4 blocks (tr,tc). S never stored; Wb quarter + dsum_part[tc*128+i] written.
__global__ __launch_bounds__(256) void l3_fused(
    const unsigned short* __restrict__ Qhi, const unsigned short* __restrict__ Qlo,
    unsigned short* __restrict__ Wb, float* __restrict__ dsum_part) {
  __shared__ __align__(16) char lds_raw[4 * 128 * PSTR * 2];
  unsigned short* sLhi = (unsigned short*)lds_raw;
  unsigned short* sLlo = sLhi + 128 * PSTR;
  unsigned short* sRhi = sLlo + 128 * PSTR;
  unsigned short* sRlo = sRhi + 128 * PSTR;
  float* sEp = (float*)lds_raw;  // [64][129]

  int tile = blockIdx.x & 3;
  int tr = tile >> 1, tc = tile & 1;
  const unsigned short* Lhi = Qhi + 65536;  // Q1 row-major
  const unsigned short* Llo = Qlo + 65536;
  const unsigned short* Rhi = Qhi;          // Q0 col-major [n][k]
  const unsigned short* Rlo = Qlo;

  int t = threadIdx.x;
  int lane = t & 63, w = t >> 6;
  int wr = (w >> 1) * 64, wc = (w & 1) * 64;
  int l15 = lane & 15, q = lane >> 4;

  f32x4 acc[4][4];
#pragma unroll
  for (int a = 0; a < 4; ++a)
#pragma unroll
    for (int b = 0; b < 4; ++b) acc[a][b] = (f32x4){0.f, 0.f, 0.f, 0.f};

  for (int kc = 0; kc < 256; kc += 32) {
    __syncthreads();
#pragma unroll
    for (int it = 0; it < 2; ++it) {
      int e = it * 2048 + t * 8;
      int row = e >> 5, k = e & 31;
      *(uint4*)(sLhi + row * PSTR + k) = *(const uint4*)(Lhi + (tr * 128 + row) * 256 + kc + k);
      *(uint4*)(sLlo + row * PSTR + k) = *(const uint4*)(Llo + (tr * 128 + row) * 256 + kc + k);
      *(uint4*)(sRhi + row * PSTR + k) = *(const uint4*)(Rhi + (tc * 128 + row) * 256 + kc + k);
      *(uint4*)(sRlo + row * PSTR + k) = *(const uint4*)(Rlo + (tc * 128 + row) * 256 + kc + k);
    }
    __syncthreads();
    int kb = q * 8;
    bf16x8 afh[4], afl[4], bfh[4], bfl[4];
#pragma unroll
    for (int rt = 0; rt < 4; ++rt) {
      int r = wr + rt * 16 + l15;
      afh[rt] = *(const bf16x8*)(sLhi + r * PSTR + kb);
      afl[rt] = *(const bf16x8*)(sLlo + r * PSTR + kb);
      int n = wc + rt * 16 + l15;
      bfh[rt] = *(const bf16x8*)(sRhi + n * PSTR + kb);
      bfl[rt] = *(const bf16x8*)(sRlo + n * PSTR + kb);
    }
#pragma unroll
    for (int rt = 0; rt < 4; ++rt)
#pragma unroll
      for (int ct = 0; ct < 4; ++ct) {
        acc[rt][ct] = MFMA(afh[rt], bfh[ct], acc[rt][ct]);
        acc[rt][ct] = MFMA(afh[rt], bfl[ct], acc[rt][ct]);
        acc[rt][ct] = MFMA(afl[rt], bfh[ct], acc[rt][ct]);
      }
  }

  // Epilogue: per 64-row phase, S-rows rbase..rbase+63, cols tc*128..+127 in sEp.
  for (int ph = 0; ph < 2; ++ph) {
    __syncthreads();
    if (wr == ph * 64) {
#pragma unroll
      for (int rt = 0; rt < 4; ++rt)
#pragma unroll
        for (int ct = 0; ct < 4; ++ct) {
          int rl = rt * 16 + q * 4;
          int col = wc + ct * 16 + l15;
#pragma unroll
          for (int rg = 0; rg < 4; ++rg) sEp[(rl + rg) * 129 + col] = acc[rt][ct][rg];
        }
    }
    __syncthreads();
    int rbase = tr * 128 + ph * 64;
    // (a) W quarter: W[n][k] = 2*S[srow][2k]; 8 (ct,ks) cells, 2 per wave.
    int ctbase = tr * 4 + ph * 2;
#pragma unroll
    for (int ci = 0; ci < 2; ++ci) {
      int cell = w * 2 + ci;  // 0..7
      int c2 = cell >> 1;
      int ct = ctbase + (c2 & 1) + ((c2 & 2) ? 8 : 0);
      int ks = 2 * tc + (cell & 1);
      int n = ct * 16 + l15;
      int srow = (n < 128) ? (2 * n) : (2 * (n - 128) + 1);
      int lr = srow - rbase;
      int lc0 = (cell & 1) * 64 + q * 16;
      float v[8];
#pragma unroll
      for (int jj = 0; jj < 8; ++jj) v[jj] = 2.0f * sEp[lr * 129 + lc0 + 2 * jj];
      unsigned int wd[4];
#pragma unroll
      for (int p2 = 0; p2 < 4; ++p2)
        wd[p2] = (unsigned int)f2bf(v[2 * p2]) | ((unsigned int)f2bf(v[2 * p2 + 1]) << 16);
      *(uint4*)(Wb + ((ct * 4 + ks) * 64 + lane) * 8) = make_uint4(wd[0], wd[1], wd[2], wd[3]);
    }
    // (b) dsum partials over this col-half: pairs ii=0..31, 8 threads each.
    {
      int ii = t >> 3, s = t & 7;
      int c0 = s * 16;
      float sum = 0.f;
#pragma unroll
      for (int c = 0; c < 16; ++c) {
        float x = sEp[(2 * ii) * 129 + c0 + c];
        float y = sEp[(2 * ii + 1) * 129 + c0 + c];
        sum += x * x + y * y;
      }
      sum += __shfl_down(sum, 4, 8);
      sum += __shfl_down(sum, 2, 8);
      sum += __shfl_down(sum, 1, 8);
      if (s == 0) dsum_part[tc * 128 + (rbase >> 1) + ii] = sum;
    }
  }
}

// ============ K4: main batched GEMM + fused epilogue (single bf16) ==========
__global__ __launch_bounds__(256) void qnn_gemm(
    const float* __restrict__ A, const unsigned short* __restrict__ Wb,
    const float* __restrict__ dsum_part, float* __restrict__ out) {
  __shared__ unsigned short sA[64 * 136];
  int t = threadIdx.x;
  int lane = t & 63, w = t >> 6;
  int wr = w >> 1, wc = w & 1;
  int l15 = lane & 15, q = lane >> 4;
  long brow0 = (long)blockIdx.x * 64;

#pragma unroll
  for (int it = 0; it < 8; ++it) {
    int e = it * 1024 + t * 4;
    int row = e >> 7, k = e & 127;
    f32x4 v = __builtin_nontemporal_load((const f32x4*)(A + brow0 * 128 + e));
    *(uint2*)(sA + row * 136 + k) = make_uint2(
        (unsigned int)f2bf(v.x) | ((unsigned int)f2bf(v.y) << 16),
        (unsigned int)f2bf(v.z) | ((unsigned int)f2bf(v.w) << 16));
  }
  __syncthreads();

  f32x4 acc[2][4][2];
#pragma unroll
  for (int rt = 0; rt < 2; ++rt)
#pragma unroll
    for (int qq = 0; qq < 4; ++qq)
#pragma unroll
      for (int xp = 0; xp < 2; ++xp) acc[rt][qq][xp] = (f32x4){0.f, 0.f, 0.f, 0.f};

#pragma unroll
  for (int ks = 0; ks < 4; ++ks) {
    int kb = ks * 32 + q * 8;
    bf16x8 a0 = *(const bf16x8*)(sA + (wr * 32 + l15) * 136 + kb);
    bf16x8 a1 = *(const bf16x8*)(sA + (wr * 32 + 16 + l15) * 136 + kb);
#pragma unroll
    for (int qq = 0; qq < 4; ++qq)
#pragma unroll
      for (int xp = 0; xp < 2; ++xp) {
        int ct = wc * 4 + qq + 8 * xp;
        bf16x8 b = *(const bf16x8*)(Wb + ((ct * 4 + ks) * 64 + lane) * 8);
        acc[0][qq][xp] = MFMA(a0, b, acc[0][qq][xp]);
        acc[1][qq][xp] = MFMA(a1, b, acc[1][qq][xp]);
      }
  }

#pragma unroll
  for (int qq = 0; qq < 4; ++qq) {
    int i = (wc * 4 + qq) * 16 + l15;
    float ds = dsum_part[i] + dsum_part[128 + i];
#pragma unroll
    for (int rt = 0; rt < 2; ++rt) {
      long row0 = brow0 + wr * 32 + rt * 16 + q * 4;
      f32x4 ax = acc[rt][qq][0];
      f32x4 ap = acc[rt][qq][1];
#pragma unroll
      for (int rg = 0; rg < 4; ++rg) {
        float val = 0.25f * (ds + ax[rg] * ax[rg] + ap[rg] * ap[rg]) - 0.5f;
        __builtin_nontemporal_store(val, &out[(row0 + rg) * 128 + i]);
      }
    }
  }
}

// ---------------- launcher ----------------------------------------------------
extern "C" void kernel_launch(void* const* d_in, const int* in_sizes, int n_in,
                              void* d_out, int out_size, void* d_ws, size_t ws_size,
                              hipStream_t stream) {
  const float* inputs = (const float*)d_in[0];   // [131072][128] f32
  const float* params = (const float*)d_in[1];   // [8][384] f32
  float* out = (float*)d_out;                    // [131072][128] f32

  unsigned short* Phi = (unsigned short*)d_ws;           // 4*65536
  unsigned short* Plo = Phi + 4 * 65536;
  unsigned short* Qhi = Plo + 4 * 65536;                 // 2*65536
  unsigned short* Qlo = Qhi + 2 * 65536;
  unsigned short* Wb = Qlo + 2 * 65536;                  // 65536
  float* dsum_part = (float*)(Wb + 65536);               // 256 f32
  // total ws use ~2.6 MiB

  l1_prod<<<16, 256, 0, stream>>>(params, Phi, Plo);
  matprod<<<8, 256, 0, stream>>>(Phi, Plo, Qhi, Qlo);
  l3_fused<<<4, 256, 0, stream>>>(Qhi, Qlo, Wb, dsum_part);
  qnn_gemm<<<2048, 256, 0, stream>>>(inputs, Wb, dsum_part, out);
}

// Round 5
// 175.261 us; speedup vs baseline: 1.2607x; 1.0508x over previous
//
#include <hip/hip_runtime.h>

// ContinuousVariableQNN: out[b,i] = 0.25*(dsum[i] + mux^2 + mup^2) - 0.5
// mu = (2*inputs) @ (S[:,0::2])^T, S = prod_l (C @ D_l) via closed-form C.
// R5: qnn_gemm pipelined persistent (4 chunks/block, dbuf LDS, reg prefetch);
// normal (cached) out-stores — R4's nt stores inflated WRITE 66->86 MB.

#define BATCH 131072
#define PSTR 40  // 32 k + 8 pad (shorts); row stride 80 B

typedef __attribute__((ext_vector_type(8))) short bf16x8;
typedef __attribute__((ext_vector_type(4))) float f32x4;

#define MFMA(a, b, c) __builtin_amdgcn_mfma_f32_16x16x32_bf16(a, b, c, 0, 0, 0)

__device__ __forceinline__ unsigned short f2bf(float f) {
  unsigned int u = __float_as_uint(f);
  u += 0x7FFFu + ((u >> 16) & 1u);
  return (unsigned short)(u >> 16);
}
__device__ __forceinline__ float bf2f(unsigned short h) {
  return __uint_as_float(((unsigned int)h) << 16);
}
__device__ __forceinline__ void pack8(const float* v, uint4& hv, uint4& lv) {
  unsigned int hw[4], lw[4];
#pragma unroll
  for (int p = 0; p < 4; ++p) {
    unsigned short h0 = f2bf(v[2 * p]), h1 = f2bf(v[2 * p + 1]);
    unsigned short l0 = f2bf(v[2 * p] - bf2f(h0)), l1 = f2bf(v[2 * p + 1] - bf2f(h1));
    hw[p] = (unsigned int)h0 | ((unsigned int)h1 << 16);
    lw[p] = (unsigned int)l0 | ((unsigned int)l1 << 16);
  }
  hv = make_uint4(hw[0], hw[1], hw[2], hw[3]);
  lv = make_uint4(lw[0], lw[1], lw[2], lw[3]);
}

// Closed-form C entry magnitude: powc[m] = 2^(-m/2) = c^m.
__device__ __forceinline__ float cxf(const float* powc, int a, int nn) {
  if (a < 127) {
    if (nn == 0) return powc[a + 1];
    if (nn <= a) return powc[a - nn + 2];
    if (nn == a + 1) return -0.70710678118654752f;
    return 0.0f;
  }
  return (nn == 0) ? powc[127] : powc[128 - nn];
}

// ============ K1: P[p] = M[2p+1] @ M[2p], M chunks built in-LDS =============
__global__ __launch_bounds__(256) void l1_prod(const float* __restrict__ params,
                                               unsigned short* __restrict__ Phi,
                                               unsigned short* __restrict__ Plo) {
  __shared__ __align__(16) char lds_raw[4 * 128 * PSTR * 2];  // 40960 B staging / sEp
  __shared__ float blkA[128][4];
  __shared__ float blkB[128][4];
  __shared__ float powc[132];
  unsigned short* sLhi = (unsigned short*)lds_raw;
  unsigned short* sLlo = sLhi + 128 * PSTR;
  unsigned short* sRhi = sLlo + 128 * PSTR;
  unsigned short* sRlo = sRhi + 128 * PSTR;
  float* sEp = (float*)lds_raw;  // epilogue [64][129]

  int bx = blockIdx.x;
  int pair = bx >> 2, tile = bx & 3;
  int tr = tile >> 1, tc = tile & 1;
  int t = threadIdx.x;
  int lane = t & 63, w = t >> 6;
  int wr = (w >> 1) * 64, wc = (w & 1) * 64;
  int l15 = lane & 15, q = lane >> 4;

  {
    int l = (t < 128) ? (2 * pair + 1) : (2 * pair);
    int nn = t & 127;
    const float* p = params + l * 384 + nn * 3;
    float th1 = p[0], r = p[1], th2 = p[2];
    float c1 = cosf(th1), s1 = sinf(th1);
    float c2 = cosf(th2), s2 = sinf(th2);
    float em = expf(-r), ep = expf(r);
    float* dst = (t < 128) ? blkA[nn] : blkB[nn];
    dst[0] = c2 * c1 * em - s2 * s1 * ep;
    dst[1] = -c2 * s1 * em - s2 * c1 * ep;
    dst[2] = s2 * c1 * em + c2 * s1 * ep;
    dst[3] = -s2 * s1 * em + c2 * c1 * ep;
    if (t < 132) powc[t] = exp2f(-0.5f * (float)t);
  }

  f32x4 acc[4][4];
#pragma unroll
  for (int a = 0; a < 4; ++a)
#pragma unroll
    for (int b = 0; b < 4; ++b) acc[a][b] = (f32x4){0.f, 0.f, 0.f, 0.f};

  for (int kc = 0; kc < 256; kc += 32) {
    __syncthreads();
#pragma unroll
    for (int it = 0; it < 2; ++it) {
      int e = it * 2048 + t * 8;
      int row = e >> 5, k0 = e & 31;
      {
        int i = tr * 128 + row;
        int a = i >> 1;
        float vv[8];
#pragma unroll
        for (int jj = 0; jj < 8; ++jj) {
          int j = kc + k0 + jj;
          int nn = j >> 1;
          vv[jj] = cxf(powc, a, nn) * blkA[nn][(i & 1) * 2 + (j & 1)];
        }
        uint4 hv, lv;
        pack8(vv, hv, lv);
        *(uint4*)(sLhi + row * PSTR + k0) = hv;
        *(uint4*)(sLlo + row * PSTR + k0) = lv;
      }
      {
        int j = tc * 128 + row;
        int nn = j >> 1;
        float b0 = blkB[nn][0 + (j & 1)];
        float b1 = blkB[nn][2 + (j & 1)];
        float vv[8];
#pragma unroll
        for (int jj = 0; jj < 8; ++jj) {
          int i = kc + k0 + jj;
          vv[jj] = cxf(powc, i >> 1, nn) * ((i & 1) ? b1 : b0);
        }
        uint4 hv, lv;
        pack8(vv, hv, lv);
        *(uint4*)(sRhi + row * PSTR + k0) = hv;
        *(uint4*)(sRlo + row * PSTR + k0) = lv;
      }
    }
    __syncthreads();
    int kb = q * 8;
    bf16x8 afh[4], afl[4], bfh[4], bfl[4];
#pragma unroll
    for (int rt = 0; rt < 4; ++rt) {
      int r = wr + rt * 16 + l15;
      afh[rt] = *(const bf16x8*)(sLhi + r * PSTR + kb);
      afl[rt] = *(const bf16x8*)(sLlo + r * PSTR + kb);
      int n = wc + rt * 16 + l15;
      bfh[rt] = *(const bf16x8*)(sRhi + n * PSTR + kb);
      bfl[rt] = *(const bf16x8*)(sRlo + n * PSTR + kb);
    }
#pragma unroll
    for (int rt = 0; rt < 4; ++rt)
#pragma unroll
      for (int ct = 0; ct < 4; ++ct) {
        acc[rt][ct] = MFMA(afh[rt], bfh[ct], acc[rt][ct]);
        acc[rt][ct] = MFMA(afh[rt], bfl[ct], acc[rt][ct]);
        acc[rt][ct] = MFMA(afl[rt], bfh[ct], acc[rt][ct]);
      }
  }

  for (int ph = 0; ph < 2; ++ph) {
    __syncthreads();
    if (wr == ph * 64) {
#pragma unroll
      for (int rt = 0; rt < 4; ++rt)
#pragma unroll
        for (int ct = 0; ct < 4; ++ct) {
          int rl = rt * 16 + q * 4;
          int col = wc + ct * 16 + l15;
#pragma unroll
          for (int rg = 0; rg < 4; ++rg) sEp[(rl + rg) * 129 + col] = acc[rt][ct][rg];
        }
    }
    __syncthreads();
    if (pair & 1) {
      int rl = t >> 2, cseg = (t & 3) * 32;
      for (int cc = 0; cc < 32; cc += 8) {
        float v[8];
#pragma unroll
        for (int jj = 0; jj < 8; ++jj) v[jj] = sEp[rl * 129 + cseg + cc + jj];
        uint4 hv, lv;
        pack8(v, hv, lv);
        int off = pair * 65536 + (tr * 128 + ph * 64 + rl) * 256 + tc * 128 + cseg + cc;
        *(uint4*)(Phi + off) = hv;
        *(uint4*)(Plo + off) = lv;
      }
    } else {
      int col = t >> 1, rseg = (t & 1) * 32;
      for (int cc = 0; cc < 32; cc += 8) {
        float v[8];
#pragma unroll
        for (int jj = 0; jj < 8; ++jj) v[jj] = sEp[(rseg + cc + jj) * 129 + col];
        uint4 hv, lv;
        pack8(v, hv, lv);
        int off = pair * 65536 + (tc * 128 + col) * 256 + tr * 128 + ph * 64 + rseg + cc;
        *(uint4*)(Phi + off) = hv;
        *(uint4*)(Plo + off) = lv;
      }
    }
  }
}

// ============ K2: Q[p] = P[2p+1] @ P[2p] (generic, LDS-staged) ==============
__global__ __launch_bounds__(256) void matprod(
    const unsigned short* __restrict__ Lhi_base, const unsigned short* __restrict__ Llo_base,
    unsigned short* __restrict__ Ohi, unsigned short* __restrict__ Olo) {
  __shared__ __align__(16) char lds_raw[4 * 128 * PSTR * 2];
  unsigned short* sLhi = (unsigned short*)lds_raw;
  unsigned short* sLlo = sLhi + 128 * PSTR;
  unsigned short* sRhi = sLlo + 128 * PSTR;
  unsigned short* sRlo = sRhi + 128 * PSTR;
  float* sEp = (float*)lds_raw;

  int bx = blockIdx.x;
  int pair = bx >> 2, tile = bx & 3;
  int tr = tile >> 1, tc = tile & 1;
  const unsigned short* Lhi = Lhi_base + (2 * pair + 1) * 65536;
  const unsigned short* Llo = Llo_base + (2 * pair + 1) * 65536;
  const unsigned short* Rhi = Lhi_base + (2 * pair) * 65536;
  const unsigned short* Rlo = Llo_base + (2 * pair) * 65536;

  int t = threadIdx.x;
  int lane = t & 63, w = t >> 6;
  int wr = (w >> 1) * 64, wc = (w & 1) * 64;
  int l15 = lane & 15, q = lane >> 4;

  f32x4 acc[4][4];
#pragma unroll
  for (int a = 0; a < 4; ++a)
#pragma unroll
    for (int b = 0; b < 4; ++b) acc[a][b] = (f32x4){0.f, 0.f, 0.f, 0.f};

  for (int kc = 0; kc < 256; kc += 32) {
    __syncthreads();
#pragma unroll
    for (int it = 0; it < 2; ++it) {
      int e = it * 2048 + t * 8;
      int row = e >> 5, k = e & 31;
      *(uint4*)(sLhi + row * PSTR + k) = *(const uint4*)(Lhi + (tr * 128 + row) * 256 + kc + k);
      *(uint4*)(sLlo + row * PSTR + k) = *(const uint4*)(Llo + (tr * 128 + row) * 256 + kc + k);
      *(uint4*)(sRhi + row * PSTR + k) = *(const uint4*)(Rhi + (tc * 128 + row) * 256 + kc + k);
      *(uint4*)(sRlo + row * PSTR + k) = *(const uint4*)(Rlo + (tc * 128 + row) * 256 + kc + k);
    }
    __syncthreads();
    int kb = q * 8;
    bf16x8 afh[4], afl[4], bfh[4], bfl[4];
#pragma unroll
    for (int rt = 0; rt < 4; ++rt) {
      int r = wr + rt * 16 + l15;
      afh[rt] = *(const bf16x8*)(sLhi + r * PSTR + kb);
      afl[rt] = *(const bf16x8*)(sLlo + r * PSTR + kb);
      int n = wc + rt * 16 + l15;
      bfh[rt] = *(const bf16x8*)(sRhi + n * PSTR + kb);
      bfl[rt] = *(const bf16x8*)(sRlo + n * PSTR + kb);
    }
#pragma unroll
    for (int rt = 0; rt < 4; ++rt)
#pragma unroll
      for (int ct = 0; ct < 4; ++ct) {
        acc[rt][ct] = MFMA(afh[rt], bfh[ct], acc[rt][ct]);
        acc[rt][ct] = MFMA(afh[rt], bfl[ct], acc[rt][ct]);
        acc[rt][ct] = MFMA(afl[rt], bfh[ct], acc[rt][ct]);
      }
  }

  for (int ph = 0; ph < 2; ++ph) {
    __syncthreads();
    if (wr == ph * 64) {
#pragma unroll
      for (int rt = 0; rt < 4; ++rt)
#pragma unroll
        for (int ct = 0; ct < 4; ++ct) {
          int rl = rt * 16 + q * 4;
          int col = wc + ct * 16 + l15;
#pragma unroll
          for (int rg = 0; rg < 4; ++rg) sEp[(rl + rg) * 129 + col] = acc[rt][ct][rg];
        }
    }
    __syncthreads();
    if (pair & 1) {
      int rl = t >> 2, cseg = (t & 3) * 32;
      for (int cc = 0; cc < 32; cc += 8) {
        float v[8];
#pragma unroll
        for (int jj = 0; jj < 8; ++jj) v[jj] = sEp[rl * 129 + cseg + cc + jj];
        uint4 hv, lv;
        pack8(v, hv, lv);
        int off = pair * 65536 + (tr * 128 + ph * 64 + rl) * 256 + tc * 128 + cseg + cc;
        *(uint4*)(Ohi + off) = hv;
        *(uint4*)(Olo + off) = lv;
      }
    } else {
      int col = t >> 1, rseg = (t & 1) * 32;
      for (int cc = 0; cc < 32; cc += 8) {
        float v[8];
#pragma unroll
        for (int jj = 0; jj < 8; ++jj) v[jj] = sEp[(rseg + cc + jj) * 129 + col];
        uint4 hv, lv;
        pack8(v, hv, lv);
        int off = pair * 65536 + (tc * 128 + col) * 256 + tr * 128 + ph * 64 + rseg + cc;
        *(uint4*)(Ohi + off) = hv;
        *(uint4*)(Olo + off) = lv;
      }
    }
  }
}

// ============ K3: S-tile = Q1 @ Q0, fused pack_W + dsum partials ============
__global__ __launch_bounds__(256) void l3_fused(
    const unsigned short* __restrict__ Qhi, const unsigned short* __restrict__ Qlo,
    unsigned short* __restrict__ Wb, float* __restrict__ dsum_part) {
  __shared__ __align__(16) char lds_raw[4 * 128 * PSTR * 2];
  unsigned short* sLhi = (unsigned short*)lds_raw;
  unsigned short* sLlo = sLhi + 128 * PSTR;
  unsigned short* sRhi = sLlo + 128 * PSTR;
  unsigned short* sRlo = sRhi + 128 * PSTR;
  float* sEp = (float*)lds_raw;  // [64][129]

  int tile = blockIdx.x & 3;
  int tr = tile >> 1, tc = tile & 1;
  const unsigned short* Lhi = Qhi + 65536;
  const unsigned short* Llo = Qlo + 65536;
  const unsigned short* Rhi = Qhi;
  const unsigned short* Rlo = Qlo;

  int t = threadIdx.x;
  int lane = t & 63, w = t >> 6;
  int wr = (w >> 1) * 64, wc = (w & 1) * 64;
  int l15 = lane & 15, q = lane >> 4;

  f32x4 acc[4][4];
#pragma unroll
  for (int a = 0; a < 4; ++a)
#pragma unroll
    for (int b = 0; b < 4; ++b) acc[a][b] = (f32x4){0.f, 0.f, 0.f, 0.f};

  for (int kc = 0; kc < 256; kc += 32) {
    __syncthreads();
#pragma unroll
    for (int it = 0; it < 2; ++it) {
      int e = it * 2048 + t * 8;
      int row = e >> 5, k = e & 31;
      *(uint4*)(sLhi + row * PSTR + k) = *(const uint4*)(Lhi + (tr * 128 + row) * 256 + kc + k);
      *(uint4*)(sLlo + row * PSTR + k) = *(const uint4*)(Llo + (tr * 128 + row) * 256 + kc + k);
      *(uint4*)(sRhi + row * PSTR + k) = *(const uint4*)(Rhi + (tc * 128 + row) * 256 + kc + k);
      *(uint4*)(sRlo + row * PSTR + k) = *(const uint4*)(Rlo + (tc * 128 + row) * 256 + kc + k);
    }
    __syncthreads();
    int kb = q * 8;
    bf16x8 afh[4], afl[4], bfh[4], bfl[4];
#pragma unroll
    for (int rt = 0; rt < 4; ++rt) {
      int r = wr + rt * 16 + l15;
      afh[rt] = *(const bf16x8*)(sLhi + r * PSTR + kb);
      afl[rt] = *(const bf16x8*)(sLlo + r * PSTR + kb);
      int n = wc + rt * 16 + l15;
      bfh[rt] = *(const bf16x8*)(sRhi + n * PSTR + kb);
      bfl[rt] = *(const bf16x8*)(sRlo + n * PSTR + kb);
    }
#pragma unroll
    for (int rt = 0; rt < 4; ++rt)
#pragma unroll
      for (int ct = 0; ct < 4; ++ct) {
        acc[rt][ct] = MFMA(afh[rt], bfh[ct], acc[rt][ct]);
        acc[rt][ct] = MFMA(afh[rt], bfl[ct], acc[rt][ct]);
        acc[rt][ct] = MFMA(afl[rt], bfh[ct], acc[rt][ct]);
      }
  }

  for (int ph = 0; ph < 2; ++ph) {
    __syncthreads();
    if (wr == ph * 64) {
#pragma unroll
      for (int rt = 0; rt < 4; ++rt)
#pragma unroll
        for (int ct = 0; ct < 4; ++ct) {
          int rl = rt * 16 + q * 4;
          int col = wc + ct * 16 + l15;
#pragma unroll
          for (int rg = 0; rg < 4; ++rg) sEp[(rl + rg) * 129 + col] = acc[rt][ct][rg];
        }
    }
    __syncthreads();
    int rbase = tr * 128 + ph * 64;
    int ctbase = tr * 4 + ph * 2;
#pragma unroll
    for (int ci = 0; ci < 2; ++ci) {
      int cell = w * 2 + ci;  // 0..7
      int c2 = cell >> 1;
      int ct = ctbase + (c2 & 1) + ((c2 & 2) ? 8 : 0);
      int ks = 2 * tc + (cell & 1);
      int n = ct * 16 + l15;
      int srow = (n < 128) ? (2 * n) : (2 * (n - 128) + 1);
      int lr = srow - rbase;
      int lc0 = (cell & 1) * 64 + q * 16;
      float v[8];
#pragma unroll
      for (int jj = 0; jj < 8; ++jj) v[jj] = 2.0f * sEp[lr * 129 + lc0 + 2 * jj];
      unsigned int wd[4];
#pragma unroll
      for (int p2 = 0; p2 < 4; ++p2)
        wd[p2] = (unsigned int)f2bf(v[2 * p2]) | ((unsigned int)f2bf(v[2 * p2 + 1]) << 16);
      *(uint4*)(Wb + ((ct * 4 + ks) * 64 + lane) * 8) = make_uint4(wd[0], wd[1], wd[2], wd[3]);
    }
    {
      int ii = t >> 3, s = t & 7;
      int c0 = s * 16;
      float sum = 0.f;
#pragma unroll
      for (int c = 0; c < 16; ++c) {
        float x = sEp[(2 * ii) * 129 + c0 + c];
        float y = sEp[(2 * ii + 1) * 129 + c0 + c];
        sum += x * x + y * y;
      }
      sum += __shfl_down(sum, 4, 8);
      sum += __shfl_down(sum, 2, 8);
      sum += __shfl_down(sum, 1, 8);
      if (s == 0) dsum_part[tc * 128 + (rbase >> 1) + ii] = sum;
    }
  }
}

// ============ K4: pipelined persistent GEMM + fused epilogue ================
// grid 512; each block does NCH=4 chunks of 64 rows; dbuf LDS, reg prefetch.
#define NCH 4
__global__ __launch_bounds__(256) void qnn_gemm(
    const float* __restrict__ A, const unsigned short* __restrict__ Wb,
    const float* __restrict__ dsum_part, float* __restrict__ out) {
  __shared__ unsigned short sA[2][64 * 136];
  int t = threadIdx.x;
  int lane = t & 63, w = t >> 6;
  int wr = w >> 1, wc = w & 1;
  int l15 = lane & 15, q = lane >> 4;
  long chunk0 = (long)blockIdx.x * NCH;

  // dsum per output column (constant across chunks)
  float ds[4];
#pragma unroll
  for (int qq = 0; qq < 4; ++qq) {
    int i = (wc * 4 + qq) * 16 + l15;
    ds[qq] = dsum_part[i] + dsum_part[128 + i];
  }

  // Preload chunk 0 -> regs -> LDS[0]
  f32x4 regs[8];
#pragma unroll
  for (int it = 0; it < 8; ++it)
    regs[it] = __builtin_nontemporal_load((const f32x4*)(A + chunk0 * 8192 + it * 1024 + t * 4));
#pragma unroll
  for (int it = 0; it < 8; ++it) {
    int e = it * 1024 + t * 4;
    int row = e >> 7, k = e & 127;
    f32x4 v = regs[it];
    *(uint2*)(&sA[0][row * 136 + k]) = make_uint2(
        (unsigned int)f2bf(v.x) | ((unsigned int)f2bf(v.y) << 16),
        (unsigned int)f2bf(v.z) | ((unsigned int)f2bf(v.w) << 16));
  }
  __syncthreads();

#pragma unroll 1
  for (int c = 0; c < NCH; ++c) {
    int buf = c & 1;
    long brow0 = (chunk0 + c) * 64;

    // Issue next chunk's loads first (stay in flight under MFMA + stores)
    if (c + 1 < NCH) {
#pragma unroll
      for (int it = 0; it < 8; ++it)
        regs[it] = __builtin_nontemporal_load(
            (const f32x4*)(A + (chunk0 + c + 1) * 8192 + it * 1024 + t * 4));
    }

    f32x4 acc[2][4][2];
#pragma unroll
    for (int rt = 0; rt < 2; ++rt)
#pragma unroll
      for (int qq = 0; qq < 4; ++qq)
#pragma unroll
        for (int xp = 0; xp < 2; ++xp) acc[rt][qq][xp] = (f32x4){0.f, 0.f, 0.f, 0.f};

#pragma unroll
    for (int ks = 0; ks < 4; ++ks) {
      int kb = ks * 32 + q * 8;
      bf16x8 a0 = *(const bf16x8*)(&sA[buf][(wr * 32 + l15) * 136 + kb]);
      bf16x8 a1 = *(const bf16x8*)(&sA[buf][(wr * 32 + 16 + l15) * 136 + kb]);
#pragma unroll
      for (int qq = 0; qq < 4; ++qq)
#pragma unroll
        for (int xp = 0; xp < 2; ++xp) {
          int ct = wc * 4 + qq + 8 * xp;
          bf16x8 b = *(const bf16x8*)(Wb + ((ct * 4 + ks) * 64 + lane) * 8);
          acc[0][qq][xp] = MFMA(a0, b, acc[0][qq][xp]);
          acc[1][qq][xp] = MFMA(a1, b, acc[1][qq][xp]);
        }
    }

    // Epilogue (normal cached stores -> full-line L2 write-back)
#pragma unroll
    for (int qq = 0; qq < 4; ++qq) {
      int i = (wc * 4 + qq) * 16 + l15;
#pragma unroll
      for (int rt = 0; rt < 2; ++rt) {
        long row0 = brow0 + wr * 32 + rt * 16 + q * 4;
        f32x4 ax = acc[rt][qq][0];
        f32x4 ap = acc[rt][qq][1];
#pragma unroll
        for (int rg = 0; rg < 4; ++rg) {
          out[(row0 + rg) * 128 + i] =
              0.25f * (ds[qq] + ax[rg] * ax[rg] + ap[rg] * ap[rg]) - 0.5f;
        }
      }
    }

    // Convert prefetched regs into the other LDS buffer
    if (c + 1 < NCH) {
#pragma unroll
      for (int it = 0; it < 8; ++it) {
        int e = it * 1024 + t * 4;
        int row = e >> 7, k = e & 127;
        f32x4 v = regs[it];
        *(uint2*)(&sA[buf ^ 1][row * 136 + k]) = make_uint2(
            (unsigned int)f2bf(v.x) | ((unsigned int)f2bf(v.y) << 16),
            (unsigned int)f2bf(v.z) | ((unsigned int)f2bf(v.w) << 16));
      }
      __syncthreads();
    }
  }
}

// ---------------- launcher ----------------------------------------------------
extern "C" void kernel_launch(void* const* d_in, const int* in_sizes, int n_in,
                              void* d_out, int out_size, void* d_ws, size_t ws_size,
                              hipStream_t stream) {
  const float* inputs = (const float*)d_in[0];   // [131072][128] f32
  const float* params = (const float*)d_in[1];   // [8][384] f32
  float* out = (float*)d_out;                    // [131072][128] f32

  unsigned short* Phi = (unsigned short*)d_ws;           // 4*65536
  unsigned short* Plo = Phi + 4 * 65536;
  unsigned short* Qhi = Plo + 4 * 65536;                 // 2*65536
  unsigned short* Qlo = Qhi + 2 * 65536;
  unsigned short* Wb = Qlo + 2 * 65536;                  // 65536
  float* dsum_part = (float*)(Wb + 65536);               // 256 f32

  l1_prod<<<16, 256, 0, stream>>>(params, Phi, Plo);
  matprod<<<8, 256, 0, stream>>>(Phi, Plo, Qhi, Qlo);
  l3_fused<<<4, 256, 0, stream>>>(Qhi, Qlo, Wb, dsum_part);
  qnn_gemm<<<BATCH / (64 * NCH), 256, 0, stream>>>(inputs, Wb, dsum_part, out);
}